// Round 4
// baseline (3218.594 us; speedup 1.0000x reference)
//
#include <hip/hip_runtime.h>

#define N_P 50000
#define N_HE 5000
#define N_E 800000
#define D_IN 128
#define D_HID 256
#define N_HEADS 4
#define HEAD_DIM 64
#define PT 8   // proteins per block in k_final

// ---------------- zero-fill workspace ----------------
__global__ void k_zero(float* __restrict__ p, unsigned n) {
    unsigned i = blockIdx.x * blockDim.x + threadIdx.x;
    unsigned stride = gridDim.x * blockDim.x;
    for (; i < n; i += stride) p[i] = 0.f;
}

// ---------------- Stage 1: he_feat[hid] += feat[pid] * w  (4 dims/thread) ----------------
__global__ void k_scatter_he(
    const float* __restrict__ feat, const float* __restrict__ edge_w,
    const int* __restrict__ edge_pid, const int* __restrict__ edge_hid,
    float* __restrict__ he_feat) {
    unsigned i = blockIdx.x * blockDim.x + threadIdx.x;
    unsigned stride = gridDim.x * blockDim.x;
    const unsigned total = (unsigned)N_E * 32u;   // 32 groups of 4 dims per edge
    for (; i < total; i += stride) {
        unsigned e = i >> 5;
        unsigned d0 = (i & 31u) * 4u;
        float w = edge_w[e];
        const float4 f = *(const float4*)(feat + (unsigned)edge_pid[e] * D_IN + d0);
        float* dst = he_feat + (unsigned)edge_hid[e] * D_IN + d0;
        atomicAdd(dst + 0, f.x * w);
        atomicAdd(dst + 1, f.y * w);
        atomicAdd(dst + 2, f.z * w);
        atomicAdd(dst + 3, f.w * w);
    }
}

// ---------------- Stage 2: attention; he_feat row scaled IN PLACE ----------------
__global__ void k_attn(
    float* __restrict__ he_feat,
    const float* __restrict__ Wh1, const float* __restrict__ bh1,
    const float* __restrict__ Wh2, const float* __restrict__ bh2,
    const float* __restrict__ Wfuse) {
    __shared__ float hef[D_IN];
    __shared__ float attnv[N_HEADS];
    __shared__ float heattn;
    int t = threadIdx.x;      // 256 threads = 4 waves; wave == head
    int head = t >> 6;
    int k = t & 63;
    for (int n = blockIdx.x; n < N_HE; n += gridDim.x) {
        if (t < D_IN) hef[t] = he_feat[n * D_IN + t];
        __syncthreads();
        float s = bh1[head * HEAD_DIM + k];
        for (int d = 0; d < D_IN; ++d)
            s += hef[d] * Wh1[(head * D_IN + d) * HEAD_DIM + k];
        s = fmaxf(s, 0.f);                          // relu
        float val = s * Wh2[head * HEAD_DIM + k];
        for (int off = 32; off; off >>= 1) val += __shfl_down(val, off);
        if (k == 0) {
            float x = val + bh2[head];
            attnv[head] = 1.f / (1.f + expf(-x));   // sigmoid
        }
        __syncthreads();
        if (t == 0) {
            float ha = 0.f;
            for (int h = 0; h < N_HEADS; ++h) ha += attnv[h] * Wfuse[h];
            heattn = ha;
        }
        __syncthreads();
        if (t < D_IN) he_feat[n * D_IN + t] = hef[t] * heattn;  // row fully staged above
        __syncthreads();
    }
}

// ---------------- Stage 3: cluster_feat[pid] += he_weighted[hid] * w  (4 dims/thread) ----------------
__global__ void k_scatter_clu(
    const float* __restrict__ he_weighted, const float* __restrict__ edge_w,
    const int* __restrict__ edge_pid, const int* __restrict__ edge_hid,
    float* __restrict__ cluster_feat) {
    unsigned i = blockIdx.x * blockDim.x + threadIdx.x;
    unsigned stride = gridDim.x * blockDim.x;
    const unsigned total = (unsigned)N_E * 32u;
    for (; i < total; i += stride) {
        unsigned e = i >> 5;
        unsigned d0 = (i & 31u) * 4u;
        float w = edge_w[e];
        const float4 f = *(const float4*)(he_weighted + (unsigned)edge_hid[e] * D_IN + d0);
        float* dst = cluster_feat + (unsigned)edge_pid[e] * D_IN + d0;
        atomicAdd(dst + 0, f.x * w);
        atomicAdd(dst + 1, f.y * w);
        atomicAdd(dst + 2, f.z * w);
        atomicAdd(dst + 3, f.w * w);
    }
}

// ---------------- Stage 4: register-blocked fused MLP, PT proteins/block ----------------
// All intermediate activations stored transposed in LDS: X[d][p], p contiguous,
// so the PT values needed per weight load are one 32B chunk (ds_read_b128 ×2,
// same-address broadcast across the wave = conflict-free).
__global__ void k_final(
    const float* __restrict__ feat, const float* __restrict__ cluster_feat,
    const float* __restrict__ Wself, const float* __restrict__ bself,
    const float* __restrict__ Wclu, const float* __restrict__ bclu,
    const float* __restrict__ Wf1, const float* __restrict__ bf1,
    const float* __restrict__ Wf2, const float* __restrict__ bf2,
    const float* __restrict__ Wf3, const float* __restrict__ bf3,
    float* __restrict__ out) {
    __shared__ float featT[D_IN * PT];        // 4 KB  [d][p]
    __shared__ float cluT [D_IN * PT];        // 4 KB
    __shared__ float catT [2 * D_IN * PT];    // 8 KB  [j][p], j in 0..255
    __shared__ float h1T  [D_HID * PT];       // 8 KB
    __shared__ float h2T  [(D_HID / 2) * PT]; // 4 KB
    __shared__ float fw   [PT * 2];           // softmax weights
    int t = threadIdx.x;

    for (int pb = blockIdx.x; pb < N_P / PT; pb += gridDim.x) {
        int p0 = pb * PT;
        const float* fbase = feat + (size_t)p0 * D_IN;
        const float* cbase = cluster_feat + (size_t)p0 * D_IN;

        // load + transpose feat / cluster rows
        #pragma unroll
        for (int k = 0; k < (PT * D_IN) / 256; ++k) {
            int i = t + k * 256;
            int p = i >> 7, d = i & 127;
            featT[d * PT + p] = fbase[i];
            cluT [d * PT + p] = cbase[i];
        }
        __syncthreads();

        // cat = [feat@Wself+bself | clu@Wclu+bclu]   (thread j = t)
        {
            int j = t;
            const float* W;  const float* act;  float b;  int jj;
            if (j < D_IN) { W = Wself; b = bself[j];        act = featT; jj = j; }
            else          { W = Wclu;  b = bclu[j - D_IN];  act = cluT;  jj = j - D_IN; }
            float acc[PT];
            #pragma unroll
            for (int p = 0; p < PT; ++p) acc[p] = b;
            for (int d = 0; d < D_IN; ++d) {
                float w = W[d * D_IN + jj];
                #pragma unroll
                for (int p = 0; p < PT; ++p) acc[p] += act[d * PT + p] * w;
            }
            #pragma unroll
            for (int p = 0; p < PT; ++p) catT[j * PT + p] = acc[p];
        }
        __syncthreads();

        // h1 = relu(cat @ Wf1 + bf1)   (thread j = t)
        {
            int j = t;
            float b = bf1[j];
            float acc[PT];
            #pragma unroll
            for (int p = 0; p < PT; ++p) acc[p] = b;
            for (int d = 0; d < 2 * D_IN; ++d) {
                float w = Wf1[d * D_HID + j];
                #pragma unroll
                for (int p = 0; p < PT; ++p) acc[p] += catT[d * PT + p] * w;
            }
            #pragma unroll
            for (int p = 0; p < PT; ++p) h1T[j * PT + p] = fmaxf(acc[p], 0.f);
        }
        __syncthreads();

        // h2 = relu(h1 @ Wf2 + bf2)   (thread: j = t&127, protein-half ph = t>>7)
        {
            int j = t & 127, ph = t >> 7;
            float b = bf2[j];
            float acc[4];
            #pragma unroll
            for (int q = 0; q < 4; ++q) acc[q] = b;
            for (int d = 0; d < D_HID; ++d) {
                float w = Wf2[d * (D_HID / 2) + j];
                #pragma unroll
                for (int q = 0; q < 4; ++q) acc[q] += h1T[d * PT + ph * 4 + q] * w;
            }
            #pragma unroll
            for (int q = 0; q < 4; ++q) h2T[j * PT + ph * 4 + q] = fmaxf(acc[q], 0.f);
        }
        __syncthreads();

        // logits + softmax  (32 threads per protein)
        {
            int p = t >> 5, k = t & 31;
            float s0 = 0.f, s1 = 0.f;
            for (int d = k; d < D_HID / 2; d += 32) {
                float h = h2T[d * PT + p];
                s0 += h * Wf3[d * 2 + 0];
                s1 += h * Wf3[d * 2 + 1];
            }
            for (int off = 16; off; off >>= 1) {
                s0 += __shfl_down(s0, off, 32);
                s1 += __shfl_down(s1, off, 32);
            }
            if (k == 0) {
                float l0 = s0 + bf3[0], l1 = s1 + bf3[1];
                float m = fmaxf(l0, l1);
                float e0 = expf(l0 - m), e1 = expf(l1 - m);
                float inv = 1.f / (e0 + e1);
                fw[p * 2 + 0] = e0 * inv;
                fw[p * 2 + 1] = e1 * inv;
            }
        }
        __syncthreads();

        // fuse + residual + relu + store
        #pragma unroll
        for (int k = 0; k < (PT * D_IN) / 256; ++k) {
            int i = t + k * 256;
            int p = i >> 7, j = i & 127;
            float fused = catT[j * PT + p] * fw[p * 2 + 0] +
                          catT[(D_IN + j) * PT + p] * fw[p * 2 + 1];
            float v = fused + featT[j * PT + p];
            out[(size_t)p0 * D_IN + i] = fmaxf(v, 0.f);
        }
        __syncthreads();
    }
}

extern "C" void kernel_launch(void* const* d_in, const int* in_sizes, int n_in,
                              void* d_out, int out_size, void* d_ws, size_t ws_size,
                              hipStream_t stream) {
    (void)in_sizes; (void)n_in; (void)out_size; (void)ws_size;
    const float* feat   = (const float*)d_in[0];
    const float* edge_w = (const float*)d_in[1];
    const float* Wself  = (const float*)d_in[2];
    const float* bself  = (const float*)d_in[3];
    const float* Wclu   = (const float*)d_in[4];
    const float* bclu   = (const float*)d_in[5];
    const float* Wh1    = (const float*)d_in[6];
    const float* bh1    = (const float*)d_in[7];
    const float* Wh2    = (const float*)d_in[8];
    const float* bh2    = (const float*)d_in[9];
    const float* Wfuse  = (const float*)d_in[10];
    const float* Wf1    = (const float*)d_in[11];
    const float* bf1_   = (const float*)d_in[12];
    const float* Wf2    = (const float*)d_in[13];
    const float* bf2_   = (const float*)d_in[14];
    const float* Wf3    = (const float*)d_in[15];
    const float* bf3_   = (const float*)d_in[16];
    const int* edge_pid = (const int*)d_in[17];
    const int* edge_hid = (const int*)d_in[18];
    float* out = (float*)d_out;

    float* he_feat      = (float*)d_ws;                         // N_HE*D_IN (weighted in place)
    float* cluster_feat = he_feat + (size_t)N_HE * D_IN;        // N_P*D_IN
    unsigned zero_elems = (unsigned)(N_HE * D_IN + N_P * D_IN);

    k_zero<<<2048, 256, 0, stream>>>((float*)d_ws, zero_elems);
    k_scatter_he<<<4096, 256, 0, stream>>>(feat, edge_w, edge_pid, edge_hid, he_feat);
    k_attn<<<2048, 256, 0, stream>>>(he_feat, Wh1, bh1, Wh2, bh2, Wfuse);
    k_scatter_clu<<<4096, 256, 0, stream>>>(he_feat, edge_w, edge_pid, edge_hid, cluster_feat);
    k_final<<<N_P / PT, 256, 0, stream>>>(feat, cluster_feat, Wself, bself, Wclu, bclu,
                                          Wf1, bf1_, Wf2, bf2_, Wf3, bf3_, out);
}

// Round 5
// 934.142 us; speedup vs baseline: 3.4455x; 3.4455x over previous
//
#include <hip/hip_runtime.h>

#define N_P 50000
#define N_HE 5000
#define N_E 800000
#define D_IN 128
#define D_HID 256
#define N_HEADS 4
#define HEAD_DIM 64
#define PT 8        // proteins per block in k_final
#define CAP_HE 320  // bucket capacity per hyperedge (mean 160)
#define CAP_P  64   // bucket capacity per protein   (mean 16)

// ---------------- zero the counters (ints) ----------------
__global__ void k_zero_int(int* __restrict__ p, unsigned n) {
    unsigned i = blockIdx.x * blockDim.x + threadIdx.x;
    unsigned stride = gridDim.x * blockDim.x;
    for (; i < n; i += stride) p[i] = 0;
}

// ---------------- bucket edges by hid and by pid ----------------
__global__ void k_bucket(
    const int* __restrict__ edge_pid, const int* __restrict__ edge_hid,
    int* __restrict__ cnt_he, int* __restrict__ cnt_p,
    int* __restrict__ list_he, int* __restrict__ list_p,
    int* __restrict__ ovf_he, int* __restrict__ ovf_he_cnt,
    int* __restrict__ ovf_p,  int* __restrict__ ovf_p_cnt) {
    unsigned e = blockIdx.x * blockDim.x + threadIdx.x;
    unsigned stride = gridDim.x * blockDim.x;
    for (; e < N_E; e += stride) {
        int h = edge_hid[e], p = edge_pid[e];
        int pos = atomicAdd(cnt_he + h, 1);
        if (pos < CAP_HE) list_he[h * CAP_HE + pos] = (int)e;
        else              ovf_he[atomicAdd(ovf_he_cnt, 1)] = (int)e;
        int pp = atomicAdd(cnt_p + p, 1);
        if (pp < CAP_P)   list_p[p * CAP_P + pp] = (int)e;
        else              ovf_p[atomicAdd(ovf_p_cnt, 1)] = (int)e;
    }
}

// ---------------- Stage 1 gather: he_feat[h] = sum feat[pid]*w ----------------
__global__ void k_gather_he(
    const float* __restrict__ feat, const float* __restrict__ edge_w,
    const int* __restrict__ edge_pid,
    const int* __restrict__ cnt_he, const int* __restrict__ list_he,
    float* __restrict__ he_feat) {
    __shared__ float tmp[D_IN];
    int h = blockIdx.x;                 // 5000 blocks
    int n = cnt_he[h]; if (n > CAP_HE) n = CAP_HE;
    const int* lst = list_he + h * CAP_HE;
    int t = threadIdx.x;                // 256 = 2 halves x 128 dims
    int half = t >> 7, d = t & 127;
    float acc = 0.f;
    for (int k = half; k < n; k += 2) {
        int e = lst[k];
        acc += feat[(unsigned)edge_pid[e] * D_IN + d] * edge_w[e];
    }
    if (half == 1) tmp[d] = acc;
    __syncthreads();
    if (half == 0) he_feat[h * D_IN + d] = acc + tmp[d];
}

// overflow fallback (normally empty): he_feat[h*128+d] += feat*w
__global__ void k_ovf_he(
    const float* __restrict__ feat, const float* __restrict__ edge_w,
    const int* __restrict__ edge_pid, const int* __restrict__ edge_hid,
    const int* __restrict__ ovf, const int* __restrict__ ovf_cnt,
    float* __restrict__ he_feat) {
    unsigned n = (unsigned)(*ovf_cnt) * D_IN;
    unsigned i = blockIdx.x * blockDim.x + threadIdx.x;
    unsigned stride = gridDim.x * blockDim.x;
    for (; i < n; i += stride) {
        int e = ovf[i >> 7];
        unsigned d = i & 127u;
        atomicAdd(he_feat + (unsigned)edge_hid[e] * D_IN + d,
                  feat[(unsigned)edge_pid[e] * D_IN + d] * edge_w[e]);
    }
}

// ---------------- Stage 2: attention; he_feat row scaled IN PLACE ----------------
__global__ void k_attn(
    float* __restrict__ he_feat,
    const float* __restrict__ Wh1, const float* __restrict__ bh1,
    const float* __restrict__ Wh2, const float* __restrict__ bh2,
    const float* __restrict__ Wfuse) {
    __shared__ float hef[D_IN];
    __shared__ float attnv[N_HEADS];
    __shared__ float heattn;
    int t = threadIdx.x;      // 256 threads = 4 waves; wave == head
    int head = t >> 6;
    int k = t & 63;
    for (int n = blockIdx.x; n < N_HE; n += gridDim.x) {
        if (t < D_IN) hef[t] = he_feat[n * D_IN + t];
        __syncthreads();
        float s = bh1[head * HEAD_DIM + k];
        for (int d = 0; d < D_IN; ++d)
            s += hef[d] * Wh1[(head * D_IN + d) * HEAD_DIM + k];
        s = fmaxf(s, 0.f);
        float val = s * Wh2[head * HEAD_DIM + k];
        for (int off = 32; off; off >>= 1) val += __shfl_down(val, off);
        if (k == 0) {
            float x = val + bh2[head];
            attnv[head] = 1.f / (1.f + expf(-x));
        }
        __syncthreads();
        if (t == 0) {
            float ha = 0.f;
            for (int h = 0; h < N_HEADS; ++h) ha += attnv[h] * Wfuse[h];
            heattn = ha;
        }
        __syncthreads();
        if (t < D_IN) he_feat[n * D_IN + t] = hef[t] * heattn;
        __syncthreads();
    }
}

// ---------------- Stage 3 gather: cluster_feat[p] = sum he_w[hid]*w ----------------
__global__ void k_gather_clu(
    const float* __restrict__ he_weighted, const float* __restrict__ edge_w,
    const int* __restrict__ edge_hid,
    const int* __restrict__ cnt_p, const int* __restrict__ list_p,
    float* __restrict__ cluster_feat) {
    int p = blockIdx.x;                 // 50000 blocks
    int n = cnt_p[p]; if (n > CAP_P) n = CAP_P;
    const int* lst = list_p + p * CAP_P;
    int d = threadIdx.x;                // 128 threads
    float acc = 0.f;
    for (int k = 0; k < n; ++k) {
        int e = lst[k];
        acc += he_weighted[(unsigned)edge_hid[e] * D_IN + d] * edge_w[e];
    }
    cluster_feat[p * D_IN + d] = acc;
}

// overflow fallback (normally empty)
__global__ void k_ovf_clu(
    const float* __restrict__ he_weighted, const float* __restrict__ edge_w,
    const int* __restrict__ edge_pid, const int* __restrict__ edge_hid,
    const int* __restrict__ ovf, const int* __restrict__ ovf_cnt,
    float* __restrict__ cluster_feat) {
    unsigned n = (unsigned)(*ovf_cnt) * D_IN;
    unsigned i = blockIdx.x * blockDim.x + threadIdx.x;
    unsigned stride = gridDim.x * blockDim.x;
    for (; i < n; i += stride) {
        int e = ovf[i >> 7];
        unsigned d = i & 127u;
        atomicAdd(cluster_feat + (unsigned)edge_pid[e] * D_IN + d,
                  he_weighted[(unsigned)edge_hid[e] * D_IN + d] * edge_w[e]);
    }
}

// ---------------- Stage 4: register-blocked fused MLP (unchanged from R4) ----------------
__global__ void k_final(
    const float* __restrict__ feat, const float* __restrict__ cluster_feat,
    const float* __restrict__ Wself, const float* __restrict__ bself,
    const float* __restrict__ Wclu, const float* __restrict__ bclu,
    const float* __restrict__ Wf1, const float* __restrict__ bf1,
    const float* __restrict__ Wf2, const float* __restrict__ bf2,
    const float* __restrict__ Wf3, const float* __restrict__ bf3,
    float* __restrict__ out) {
    __shared__ float featT[D_IN * PT];
    __shared__ float cluT [D_IN * PT];
    __shared__ float catT [2 * D_IN * PT];
    __shared__ float h1T  [D_HID * PT];
    __shared__ float h2T  [(D_HID / 2) * PT];
    __shared__ float fw   [PT * 2];
    int t = threadIdx.x;

    for (int pb = blockIdx.x; pb < N_P / PT; pb += gridDim.x) {
        int p0 = pb * PT;
        const float* fbase = feat + (size_t)p0 * D_IN;
        const float* cbase = cluster_feat + (size_t)p0 * D_IN;

        #pragma unroll
        for (int k = 0; k < (PT * D_IN) / 256; ++k) {
            int i = t + k * 256;
            int p = i >> 7, d = i & 127;
            featT[d * PT + p] = fbase[i];
            cluT [d * PT + p] = cbase[i];
        }
        __syncthreads();

        {   // cat = [feat@Wself+bself | clu@Wclu+bclu]
            int j = t;
            const float* W;  const float* act;  float b;  int jj;
            if (j < D_IN) { W = Wself; b = bself[j];        act = featT; jj = j; }
            else          { W = Wclu;  b = bclu[j - D_IN];  act = cluT;  jj = j - D_IN; }
            float acc[PT];
            #pragma unroll
            for (int p = 0; p < PT; ++p) acc[p] = b;
            for (int d = 0; d < D_IN; ++d) {
                float w = W[d * D_IN + jj];
                #pragma unroll
                for (int p = 0; p < PT; ++p) acc[p] += act[d * PT + p] * w;
            }
            #pragma unroll
            for (int p = 0; p < PT; ++p) catT[j * PT + p] = acc[p];
        }
        __syncthreads();

        {   // h1 = relu(cat @ Wf1 + bf1)
            int j = t;
            float b = bf1[j];
            float acc[PT];
            #pragma unroll
            for (int p = 0; p < PT; ++p) acc[p] = b;
            for (int d = 0; d < 2 * D_IN; ++d) {
                float w = Wf1[d * D_HID + j];
                #pragma unroll
                for (int p = 0; p < PT; ++p) acc[p] += catT[d * PT + p] * w;
            }
            #pragma unroll
            for (int p = 0; p < PT; ++p) h1T[j * PT + p] = fmaxf(acc[p], 0.f);
        }
        __syncthreads();

        {   // h2 = relu(h1 @ Wf2 + bf2)
            int j = t & 127, ph = t >> 7;
            float b = bf2[j];
            float acc[4];
            #pragma unroll
            for (int q = 0; q < 4; ++q) acc[q] = b;
            for (int d = 0; d < D_HID; ++d) {
                float w = Wf2[d * (D_HID / 2) + j];
                #pragma unroll
                for (int q = 0; q < 4; ++q) acc[q] += h1T[d * PT + ph * 4 + q] * w;
            }
            #pragma unroll
            for (int q = 0; q < 4; ++q) h2T[j * PT + ph * 4 + q] = fmaxf(acc[q], 0.f);
        }
        __syncthreads();

        {   // logits + softmax (32 threads per protein)
            int p = t >> 5, k = t & 31;
            float s0 = 0.f, s1 = 0.f;
            for (int d = k; d < D_HID / 2; d += 32) {
                float h = h2T[d * PT + p];
                s0 += h * Wf3[d * 2 + 0];
                s1 += h * Wf3[d * 2 + 1];
            }
            for (int off = 16; off; off >>= 1) {
                s0 += __shfl_down(s0, off, 32);
                s1 += __shfl_down(s1, off, 32);
            }
            if (k == 0) {
                float l0 = s0 + bf3[0], l1 = s1 + bf3[1];
                float m = fmaxf(l0, l1);
                float e0 = expf(l0 - m), e1 = expf(l1 - m);
                float inv = 1.f / (e0 + e1);
                fw[p * 2 + 0] = e0 * inv;
                fw[p * 2 + 1] = e1 * inv;
            }
        }
        __syncthreads();

        #pragma unroll
        for (int k = 0; k < (PT * D_IN) / 256; ++k) {
            int i = t + k * 256;
            int p = i >> 7, j = i & 127;
            float fused = catT[j * PT + p] * fw[p * 2 + 0] +
                          catT[(D_IN + j) * PT + p] * fw[p * 2 + 1];
            float v = fused + featT[j * PT + p];
            out[(size_t)p0 * D_IN + i] = fmaxf(v, 0.f);
        }
        __syncthreads();
    }
}

extern "C" void kernel_launch(void* const* d_in, const int* in_sizes, int n_in,
                              void* d_out, int out_size, void* d_ws, size_t ws_size,
                              hipStream_t stream) {
    (void)in_sizes; (void)n_in; (void)out_size; (void)ws_size;
    const float* feat   = (const float*)d_in[0];
    const float* edge_w = (const float*)d_in[1];
    const float* Wself  = (const float*)d_in[2];
    const float* bself  = (const float*)d_in[3];
    const float* Wclu   = (const float*)d_in[4];
    const float* bclu   = (const float*)d_in[5];
    const float* Wh1    = (const float*)d_in[6];
    const float* bh1    = (const float*)d_in[7];
    const float* Wh2    = (const float*)d_in[8];
    const float* bh2    = (const float*)d_in[9];
    const float* Wfuse  = (const float*)d_in[10];
    const float* Wf1    = (const float*)d_in[11];
    const float* bf1_   = (const float*)d_in[12];
    const float* Wf2    = (const float*)d_in[13];
    const float* bf2_   = (const float*)d_in[14];
    const float* Wf3    = (const float*)d_in[15];
    const float* bf3_   = (const float*)d_in[16];
    const int* edge_pid = (const int*)d_in[17];
    const int* edge_hid = (const int*)d_in[18];
    float* out = (float*)d_out;

    // ---- workspace carve-up (floats then ints; all 4B-aligned) ----
    float* he_feat      = (float*)d_ws;                          // 5000*128
    float* cluster_feat = he_feat + (size_t)N_HE * D_IN;         // 50000*128
    int* ibase   = (int*)(cluster_feat + (size_t)N_P * D_IN);
    int* cnt_he  = ibase;                    // 5000
    int* cnt_p   = cnt_he + N_HE;            // 50000
    int* ovf_he_cnt = cnt_p + N_P;           // 1
    int* ovf_p_cnt  = ovf_he_cnt + 1;        // 1
    int* list_he = ovf_p_cnt + 1;            // 5000*CAP_HE
    int* list_p  = list_he + (size_t)N_HE * CAP_HE;  // 50000*CAP_P
    int* ovf_he  = list_p + (size_t)N_P * CAP_P;     // N_E
    int* ovf_p   = ovf_he + N_E;                     // N_E

    k_zero_int<<<64, 256, 0, stream>>>(cnt_he, (unsigned)(N_HE + N_P + 2));
    k_bucket<<<2048, 256, 0, stream>>>(edge_pid, edge_hid, cnt_he, cnt_p,
                                       list_he, list_p, ovf_he, ovf_he_cnt, ovf_p, ovf_p_cnt);
    k_gather_he<<<N_HE, 256, 0, stream>>>(feat, edge_w, edge_pid, cnt_he, list_he, he_feat);
    k_ovf_he<<<256, 256, 0, stream>>>(feat, edge_w, edge_pid, edge_hid, ovf_he, ovf_he_cnt, he_feat);
    k_attn<<<2048, 256, 0, stream>>>(he_feat, Wh1, bh1, Wh2, bh2, Wfuse);
    k_gather_clu<<<N_P, 128, 0, stream>>>(he_feat, edge_w, edge_hid, cnt_p, list_p, cluster_feat);
    k_ovf_clu<<<256, 256, 0, stream>>>(he_feat, edge_w, edge_pid, edge_hid, ovf_p, ovf_p_cnt, cluster_feat);
    k_final<<<N_P / PT, 256, 0, stream>>>(feat, cluster_feat, Wself, bself, Wclu, bclu,
                                          Wf1, bf1_, Wf2, bf2_, Wf3, bf3_, out);
}